// Round 5
// baseline (369.928 us; speedup 1.0000x reference)
//
#include <hip/hip_runtime.h>

// QLSTM recurrence on MI355X — round 7 (resubmit; round-4 bench was an infra
// container failure, kernel never ran — code audit found no defect).
// Skeleton = round 6 (4 waves / 4 SIMDs, lane g owns h[g], fused-DPP tree,
// raw lgkm-only barrier, window-filled LDS read, unroll x2, merged-rcp
// pre-scaled gates). Round-4 HW data confirms the exchange beats replication.
//
// Round-7 changes — shorten the POST-barrier serial tail:
//  1. Per-wave aq-dot PRE-barrier: after the tree, lanes 48-63 hold full wave
//     sums and m=l&15 indexes the q-block -> each wave writes its 16 scalar
//     aq-contributions (4B/lane). Post-barrier = ds_read_b128 + 2 adds + exp2
//     (was: 4x read + 6 pk-combine + depth-3 dot).
//  2. qown affine folded into z-weights: broadcast q' = rcp(1+exp2(aq));
//     wo2 = -2*sk*wo, bo2 = sk*(bo + sum_r wo) precomputed.
//  3. tau/owh split: o = rcp(1+e3) is ready before Ec; owh = o*wh computed
//     under the Ec exp2 latency; next-step p = fma(tau, owh, xq). The o-mul
//     leaves the h->p chain; store h = tau*o off-chain.

#define B_ 256
#define T_ 512
#define F_ 128
#define H_ 256

#define SC1 1.442695041f    // log2(e)
#define SC2 2.885390082f    // 2*log2(e)
#define ISC2 0.3465735903f  // 1/SC2

__device__ __forceinline__ float rcp_f(float x)  { return __builtin_amdgcn_rcpf(x); }
__device__ __forceinline__ float exp2_f(float x) { return __builtin_amdgcn_exp2f(x); }

__device__ __forceinline__ float rl(float v, int lane) {
    return __int_as_float(__builtin_amdgcn_readlane(__float_as_int(v), lane));
}

// Fused 64-lane sum of 4 independent values; results valid at lanes 48-63
// (row 3 accumulates the full sum after row_bcast15 + row_bcast31).
// 6 levels x 4 interleaved chains: DPP consumer >=4 instrs from producer
// (VALU->DPP hazard covered by construction; s_nop 1 guards the entry).
__device__ __forceinline__ void tree4(float& p0, float& p1, float& p2, float& p3) {
    asm volatile(
        "s_nop 1\n\t"
        "v_add_f32_dpp %0, %0, %0 quad_perm:[1,0,3,2] row_mask:0xf bank_mask:0xf\n\t"
        "v_add_f32_dpp %1, %1, %1 quad_perm:[1,0,3,2] row_mask:0xf bank_mask:0xf\n\t"
        "v_add_f32_dpp %2, %2, %2 quad_perm:[1,0,3,2] row_mask:0xf bank_mask:0xf\n\t"
        "v_add_f32_dpp %3, %3, %3 quad_perm:[1,0,3,2] row_mask:0xf bank_mask:0xf\n\t"
        "v_add_f32_dpp %0, %0, %0 quad_perm:[2,3,0,1] row_mask:0xf bank_mask:0xf\n\t"
        "v_add_f32_dpp %1, %1, %1 quad_perm:[2,3,0,1] row_mask:0xf bank_mask:0xf\n\t"
        "v_add_f32_dpp %2, %2, %2 quad_perm:[2,3,0,1] row_mask:0xf bank_mask:0xf\n\t"
        "v_add_f32_dpp %3, %3, %3 quad_perm:[2,3,0,1] row_mask:0xf bank_mask:0xf\n\t"
        "v_add_f32_dpp %0, %0, %0 row_half_mirror row_mask:0xf bank_mask:0xf\n\t"
        "v_add_f32_dpp %1, %1, %1 row_half_mirror row_mask:0xf bank_mask:0xf\n\t"
        "v_add_f32_dpp %2, %2, %2 row_half_mirror row_mask:0xf bank_mask:0xf\n\t"
        "v_add_f32_dpp %3, %3, %3 row_half_mirror row_mask:0xf bank_mask:0xf\n\t"
        "v_add_f32_dpp %0, %0, %0 row_mirror row_mask:0xf bank_mask:0xf\n\t"
        "v_add_f32_dpp %1, %1, %1 row_mirror row_mask:0xf bank_mask:0xf\n\t"
        "v_add_f32_dpp %2, %2, %2 row_mirror row_mask:0xf bank_mask:0xf\n\t"
        "v_add_f32_dpp %3, %3, %3 row_mirror row_mask:0xf bank_mask:0xf\n\t"
        "v_add_f32_dpp %0, %0, %0 row_bcast:15 row_mask:0xf bank_mask:0xf\n\t"
        "v_add_f32_dpp %1, %1, %1 row_bcast:15 row_mask:0xf bank_mask:0xf\n\t"
        "v_add_f32_dpp %2, %2, %2 row_bcast:15 row_mask:0xf bank_mask:0xf\n\t"
        "v_add_f32_dpp %3, %3, %3 row_bcast:15 row_mask:0xf bank_mask:0xf\n\t"
        "v_add_f32_dpp %0, %0, %0 row_bcast:31 row_mask:0xf bank_mask:0xf\n\t"
        "v_add_f32_dpp %1, %1, %1 row_bcast:31 row_mask:0xf bank_mask:0xf\n\t"
        "v_add_f32_dpp %2, %2, %2 row_bcast:31 row_mask:0xf bank_mask:0xf\n\t"
        "v_add_f32_dpp %3, %3, %3 row_bcast:31 row_mask:0xf bank_mask:0xf"
        : "+v"(p0), "+v"(p1), "+v"(p2), "+v"(p3));
}

// LDS-only barrier: drain LDS ops, sync waves. Does NOT drain vmcnt.
__device__ __forceinline__ void lds_barrier() {
    asm volatile("s_waitcnt lgkmcnt(0)\n\ts_barrier" ::: "memory");
}

__global__ __launch_bounds__(256, 1) void qlstm_kernel(
    const float* __restrict__ x,      // [B,T,F]
    const float* __restrict__ W_in,   // [H+F, 4] (row = float4)
    const float* __restrict__ b_in,   // [4]
    const float* __restrict__ Wq,     // [4,4,4]
    const float* __restrict__ bq,     // [4,4]
    const float* __restrict__ W_out,  // [4,H]
    const float* __restrict__ b_out,  // [H]
    float* __restrict__ out)          // [B*T*H] ++ [B*H] ++ [B*H]
{
    const int b = blockIdx.x;
    const int g = threadIdx.x;   // 0..255 — my h index
    const int w = g >> 6;        // wave 0..3
    const int l = g & 63;

    // Exchange: per-wave aq contributions. partA[slot][m][w], 512 B.
    __shared__ float partA[2][16][4];

    const float4* Win4 = (const float4*)W_in;

    float4 t4 = Win4[g];
    float wh[4] = {t4.x, t4.y, t4.z, t4.w};

    const bool has_x = (w < 2);
    float wx[4] = {0.f, 0.f, 0.f, 0.f};
    if (has_x) {
        float4 u4 = Win4[H_ + g];
        wx[0] = u4.x; wx[1] = u4.y; wx[2] = u4.z; wx[3] = u4.w;
    }

    // z' weights with BOTH the per-gate scale sk and the q-affine folded in:
    //   z'[k] = bo2[k] + sum_r q'[k4+r] * wo2[k][r],  q' = rcp(1+exp2(aq))
    //   wo2[k][r] = -2*sk[k]*wo[r],  bo2[k] = sk[k]*(bo + sum_r wo[r])
    const float sk[4] = {-SC1, -SC1, SC2, -SC1};
    float wo2[4][4];
    float bo2[4];
    {
        const float bo = b_out[g];
        float wos[4];
        float wsum = 0.f;
#pragma unroll
        for (int r = 0; r < 4; ++r) { wos[r] = W_out[r * H_ + g]; wsum += wos[r]; }
#pragma unroll
        for (int k = 0; k < 4; ++k) {
            bo2[k] = sk[k] * (bo + wsum);
#pragma unroll
            for (int r = 0; r < 4; ++r) wo2[k][r] = -2.0f * sk[k] * wos[r];
        }
    }

    float bin[4];
#pragma unroll
    for (int q = 0; q < 4; ++q) bin[q] = b_in[q];

    // Lane-distributed q-block (pre-scaled by SC2, b_in folded).
    const int m = l & 15, qk = m >> 2, qr = m & 3;
    float wql[4];
#pragma unroll
    for (int s = 0; s < 4; ++s) wql[s] = Wq[qk * 16 + s * 4 + qr];
    float bql = bq[qk * 4 + qr];
#pragma unroll
    for (int s = 0; s < 4; ++s) bql = fmaf(bin[s], wql[s], bql);
    bql *= SC2;
#pragma unroll
    for (int s = 0; s < 4; ++s) wql[s] *= SC2;
    const float bqlw = (w == 0) ? bql : 0.0f;   // bias added by wave 0 only

    // Recurrent state: tau = tanh(c), C = SC2*c, owh = o*wh.
    float tau = 0.f, C = 0.f;
    float owh0 = 0.f, owh1 = 0.f, owh2 = 0.f, owh3 = 0.f;

    const float* xp = x + (size_t)b * T_ * F_ + g;
    float xq0 = 0.f, xq1 = 0.f, xq2 = 0.f, xq3 = 0.f;
    float xv1 = 0.f;
    if (has_x) {
        const float xv0 = xp[0];
        xv1 = xp[F_];
        xq0 = xv0 * wx[0]; xq1 = xv0 * wx[1];
        xq2 = xv0 * wx[2]; xq3 = xv0 * wx[3];
    }

    float* outp = out + (size_t)b * T_ * H_ + g;
    float o_last = 0.f;

#define STEP(t, slot)                                                          \
    {                                                                          \
        float p0 = fmaf(tau, owh0, xq0);                                       \
        float p1 = fmaf(tau, owh1, xq1);                                       \
        float p2 = fmaf(tau, owh2, xq2);                                       \
        float p3 = fmaf(tau, owh3, xq3);                                       \
        tree4(p0, p1, p2, p3);                                                 \
        /* per-wave aq contribution; valid at lanes 48-63 (m = l-48) */        \
        float u = fmaf(p0, wql[0], bqlw);                                      \
        const float vv = fmaf(p3, wql[3], p2 * wql[2]);                        \
        u = fmaf(p1, wql[1], u);                                               \
        const float aqw = u + vv;                                              \
        if (l >= 48) partA[slot][m][w] = aqw;                                  \
        lds_barrier();                                                         \
        const float4 a = *(const float4*)&partA[slot][m][0];                   \
        /* window filler: next step's x products + prefetch (y-independent) */ \
        if (has_x) {                                                           \
            xq0 = xv1 * wx[0]; xq1 = xv1 * wx[1];                              \
            xq2 = xv1 * wx[2]; xq3 = xv1 * wx[3];                              \
            int tn = (t) + 2; if (tn >= T_) tn = T_ - 1;                       \
            xv1 = xp[(size_t)tn * F_];                                         \
        }                                                                      \
        const float aq = (a.x + a.y) + (a.z + a.w);                            \
        const float qp = rcp_f(1.0f + exp2_f(aq));   /* q' (affine folded) */  \
        float qs[16];                                                          \
        _Pragma("unroll")                                                      \
        for (int i = 0; i < 16; ++i) qs[i] = rl(qp, i);                        \
        float zp[4];                                                           \
        _Pragma("unroll")                                                      \
        for (int k = 0; k < 4; ++k) {                                          \
            float za = fmaf(qs[k * 4 + 0], wo2[k][0], bo2[k]);                 \
            const float zb = fmaf(qs[k * 4 + 1], wo2[k][1],                    \
                                  qs[k * 4 + 2] * wo2[k][2]);                  \
            za = fmaf(qs[k * 4 + 3], wo2[k][3], za);                           \
            zp[k] = za + zb;                                                   \
        }                                                                      \
        const float e0 = exp2_f(zp[0]);                                        \
        const float e1 = exp2_f(zp[1]);                                        \
        const float E2 = exp2_f(zp[2]);                                        \
        const float e3 = exp2_f(zp[3]);                                        \
        const float num2 = fmaf(SC2, E2, -SC2);                                \
        const float IG2  = num2 * rcp_f((1.0f + e0) * (1.0f + E2));            \
        const float fg   = rcp_f(1.0f + e1);                                   \
        C = fmaf(fg, C, IG2);                                                  \
        /* o-gate path is off the C->Ec chain: fill the exp2 latency */        \
        const float o = rcp_f(1.0f + e3);                                      \
        owh0 = o * wh[0]; owh1 = o * wh[1];                                    \
        owh2 = o * wh[2]; owh3 = o * wh[3];                                    \
        const float Ec = exp2_f(C);                                            \
        tau = (Ec - 1.0f) * rcp_f(1.0f + Ec);                                  \
        o_last = o;                                                            \
        outp[(size_t)(t) * H_] = tau * o;   /* store off-chain */              \
    }

    for (int t = 0; t < T_; t += 2) {
        STEP(t, 0);
        STEP(t + 1, 1);
    }
#undef STEP

    float* hT = out + (size_t)B_ * T_ * H_;
    hT[(size_t)b * H_ + g] = tau * o_last;
    hT[(size_t)B_ * H_ + (size_t)b * H_ + g] = C * ISC2;
}

extern "C" void kernel_launch(void* const* d_in, const int* in_sizes, int n_in,
                              void* d_out, int out_size, void* d_ws, size_t ws_size,
                              hipStream_t stream) {
    const float* x     = (const float*)d_in[0];
    const float* W_in  = (const float*)d_in[1];
    const float* b_in  = (const float*)d_in[2];
    const float* Wq    = (const float*)d_in[3];
    const float* bq    = (const float*)d_in[4];
    const float* W_out = (const float*)d_in[5];
    const float* b_out = (const float*)d_in[6];
    float* out = (float*)d_out;

    qlstm_kernel<<<dim3(B_), dim3(256), 0, stream>>>(
        x, W_in, b_in, Wq, bq, W_out, b_out, out);
}